// Round 5
// baseline (548.760 us; speedup 1.0000x reference)
//
#include <hip/hip_runtime.h>
#include <hip/hip_fp16.h>

#define RES 512
#define FEAT 32
#define PLANE_ELEMS (RES * RES)                 // 262144
#define PLANE_CH_ELEMS (FEAT * PLANE_ELEMS)     // per plane (ch-first fp32)
#define PTS_PER_BLOCK 64
#define OUT_DIM 135
#define TILE_HALVES (PTS_PER_BLOCK * OUT_DIM)   // 8640 halves = 17280 B

#define FP8_SCALE 1024.0f
#define FP8_INV_SCALE (1.0f / 1024.0f)

#define NCELLS 4096                              // 16^3 Morton cells
#define HIST_BLOCKS 512

// ws layout (ws is ~2.1 GB; we use < 42 MB)
#define WS_PLANES 0u
#define WS_CNT    (24u << 20)                    // 4096 u32
#define WS_CURSOR ((24u << 20) + 16384u)         // 4096 u32
#define WS_SBUCK  (25u << 20)                    // npts x uint4 (16 MB)

typedef float floatx2 __attribute__((ext_vector_type(2)));
typedef float floatx4 __attribute__((ext_vector_type(4)));

// ---------------------------------------------------------------------------
// helpers
// ---------------------------------------------------------------------------
__device__ __forceinline__ unsigned spread4(unsigned v) {
    return (v & 1u) | ((v & 2u) << 2) | ((v & 4u) << 4) | ((v & 8u) << 6);
}

__device__ __forceinline__ void point_transform(
        const float* __restrict__ p, const float* __restrict__ aabb, int i,
        float& tx, float& ty, float& tz) {
    float a0x = aabb[0], a0y = aabb[1], a0z = aabb[2];
    float a1x = aabb[3], a1y = aabb[4], a1z = aabb[5];
    tx = fminf(fmaxf((p[3 * (size_t)i + 0] - a0x) / (a1x - a0x), 0.0f), 1.0f);
    ty = fminf(fmaxf((p[3 * (size_t)i + 1] - a0y) / (a1y - a0y), 0.0f), 1.0f);
    tz = fminf(fmaxf((p[3 * (size_t)i + 2] - a0z) / (a1z - a0z), 0.0f), 1.0f);
}

__device__ __forceinline__ unsigned cell_of(float tx, float ty, float tz) {
    unsigned cx = min(15u, (unsigned)(tx * 16.0f));
    unsigned cy = min(15u, (unsigned)(ty * 16.0f));
    unsigned cz = min(15u, (unsigned)(tz * 16.0f));
    return spread4(cx) | (spread4(cy) << 1) | (spread4(cz) << 2);
}

// ---------------------------------------------------------------------------
// Kernel 1: triplane [3][32][512][512] fp32 -> ws [3][512][512][32] fp8 e4m3
// ---------------------------------------------------------------------------
__global__ __launch_bounds__(256) void transpose_to_chlast_fp8(
        const float* __restrict__ tri, unsigned char* __restrict__ ws) {
    int idx = blockIdx.x * 256 + threadIdx.x;   // 0 .. 3*512*512-1
    int pl = idx >> 18;
    int rem = idx & (PLANE_ELEMS - 1);
    const float* src = tri + (size_t)pl * PLANE_CH_ELEMS + rem;

    float v[32];
#pragma unroll
    for (int c = 0; c < 32; ++c)
        v[c] = __builtin_nontemporal_load(src + (size_t)c * PLANE_ELEMS) * FP8_SCALE;

    union { unsigned int w[8]; uint4 u[2]; } buf;
#pragma unroll
    for (int d = 0; d < 8; ++d) {
        int w = 0;
        w = __builtin_amdgcn_cvt_pk_fp8_f32(v[4 * d + 0], v[4 * d + 1], w, false);
        w = __builtin_amdgcn_cvt_pk_fp8_f32(v[4 * d + 2], v[4 * d + 3], w, true);
        buf.w[d] = (unsigned int)w;
    }

    uint4* dst = (uint4*)(ws + (size_t)idx * FEAT);
    dst[0] = buf.u[0];
    dst[1] = buf.u[1];
}

// ---------------------------------------------------------------------------
// Kernel 2: histogram of points per Morton cell (LDS-aggregated).
// ---------------------------------------------------------------------------
__global__ __launch_bounds__(256) void hist_kernel(
        const float* __restrict__ p, const float* __restrict__ aabb,
        unsigned* __restrict__ cnt, int npts) {
    __shared__ unsigned h[NCELLS];
    for (int i = threadIdx.x; i < NCELLS; i += 256) h[i] = 0;
    __syncthreads();
    for (int i = blockIdx.x * 256 + threadIdx.x; i < npts; i += gridDim.x * 256) {
        float tx, ty, tz;
        point_transform(p, aabb, i, tx, ty, tz);
        atomicAdd(&h[cell_of(tx, ty, tz)], 1u);
    }
    __syncthreads();
    for (int i = threadIdx.x; i < NCELLS; i += 256) {
        unsigned v = h[i];
        if (v) atomicAdd(&cnt[i], v);
    }
}

// ---------------------------------------------------------------------------
// Kernel 3: exclusive scan of 4096 counters -> cursor (single block).
// ---------------------------------------------------------------------------
__global__ __launch_bounds__(256) void scan_kernel(
        const unsigned* __restrict__ cnt, unsigned* __restrict__ cursor) {
    __shared__ unsigned partial[256];
    int t = threadIdx.x;
    unsigned local[16];
    unsigned sum = 0;
#pragma unroll
    for (int k = 0; k < 16; ++k) { local[k] = sum; sum += cnt[t * 16 + k]; }
    partial[t] = sum;
    __syncthreads();
    for (int off = 1; off < 256; off <<= 1) {
        unsigned v = partial[t];
        if (t >= off) v += partial[t - off];
        __syncthreads();
        partial[t] = v;
        __syncthreads();
    }
    unsigned base = (t == 0) ? 0u : partial[t - 1];
#pragma unroll
    for (int k = 0; k < 16; ++k) cursor[t * 16 + k] = base + local[k];
}

// ---------------------------------------------------------------------------
// Kernel 4: scatter points into Morton-sorted compact array.
// Block-contiguous partition; LDS rank + one range-reserve atomic per
// (block, nonzero cell) keeps hot-cell atomic chains short.
// ---------------------------------------------------------------------------
#define SCAT_KMAX 8
__global__ __launch_bounds__(256) void scatter_kernel(
        const float* __restrict__ p, const float* __restrict__ aabb,
        unsigned* __restrict__ cursor, uint4* __restrict__ sbuck, int npts) {
    __shared__ unsigned hcnt[NCELLS];
    __shared__ unsigned hbase[NCELLS];
    for (int i = threadIdx.x; i < NCELLS; i += 256) hcnt[i] = 0;
    __syncthreads();

    int chunk = (npts + gridDim.x - 1) / gridDim.x;
    int beg = blockIdx.x * chunk;
    int end = min(npts, beg + chunk);

    unsigned myCell[SCAT_KMAX], myRank[SCAT_KMAX];
    int myPt[SCAT_KMAX];
    int n = 0;
    for (int i = beg + threadIdx.x; i < end && n < SCAT_KMAX; i += 256) {
        float tx, ty, tz;
        point_transform(p, aabb, i, tx, ty, tz);
        unsigned c = cell_of(tx, ty, tz);
        myCell[n] = c;
        myRank[n] = atomicAdd(&hcnt[c], 1u);
        myPt[n] = i;
        ++n;
    }
    __syncthreads();
    for (int i = threadIdx.x; i < NCELLS; i += 256) {
        unsigned v = hcnt[i];
        hbase[i] = v ? atomicAdd(&cursor[i], v) : 0u;
    }
    __syncthreads();
    for (int k = 0; k < n; ++k) {
        int i = myPt[k];
        float tx, ty, tz;
        point_transform(p, aabb, i, tx, ty, tz);
        float X = 2.0f * tx - 1.0f, Y = 2.0f * ty - 1.0f, Z = 2.0f * tz - 1.0f;
        unsigned slot = hbase[myCell[k]] + myRank[k];
        uint4 v;
        v.x = __float_as_uint(X); v.y = __float_as_uint(Y);
        v.z = __float_as_uint(Z); v.w = (unsigned)i;
        sbuck[slot] = v;
    }
}

// ---------------------------------------------------------------------------
// Kernel 5: sample + posenc over Morton-sorted points.
// ---------------------------------------------------------------------------
__global__ __launch_bounds__(256, 6) void triplane_sample_sorted(
        const unsigned char* __restrict__ ws, const uint4* __restrict__ sbuck,
        float* __restrict__ out, int npts, int nb) {
    __shared__ __align__(16) __half tile[TILE_HALVES];   // 17280 B
    __shared__ int sIdx[PTS_PER_BLOCK];

    // bijective chunked XCD swizzle: each XCD gets a contiguous Morton range
    int orig = blockIdx.x;
    int xcd = orig & 7, j = orig >> 3;
    int q = nb >> 3, r = nb & 7;
    int wg = (xcd < r ? xcd * (q + 1) : r * (q + 1) + (xcd - r) * q) + j;

    int base = wg * PTS_PER_BLOCK;
    int m = min(PTS_PER_BLOCK, npts - base);
    if (m <= 0) return;

    const int t = threadIdx.x;
    const int g = t >> 2;         // point row within block
    const int s = t & 3;          // sub-thread (channel chunk)
    const bool act = g < m;

    float X = 0.f, Y = 0.f, Z = 0.f;
    if (act) {
        uint4 pt = sbuck[base + g];
        X = __uint_as_float(pt.x);
        Y = __uint_as_float(pt.y);
        Z = __uint_as_float(pt.z);
        if (s == 0) sIdx[g] = (int)pt.w;
    }

    if (act) {
        // plane 0: (gx=X, gy=Y); plane 1: (gx=Y, gy=Z); plane 2: (gx=X, gy=Z)
        float gxs[3] = {X, Y, X};
        float gys[3] = {Y, Z, Z};
        unsigned o00[3], o01[3], o10[3], o11[3];
        float wxv[3], wyv[3];
#pragma unroll
        for (int pl = 0; pl < 3; ++pl) {
            float fx = (gxs[pl] + 1.0f) * (0.5f * (RES - 1));
            float fy = (gys[pl] + 1.0f) * (0.5f * (RES - 1));
            float x0f = floorf(fx), y0f = floorf(fy);
            wxv[pl] = fx - x0f;
            wyv[pl] = fy - y0f;
            int x0 = min(max((int)x0f, 0), RES - 1);
            int x1 = min(x0 + 1, RES - 1);
            int y0 = min(max((int)y0f, 0), RES - 1);
            int y1 = min(y0 + 1, RES - 1);
            unsigned bpl = (unsigned)pl * (PLANE_ELEMS * FEAT);
            unsigned r0 = bpl + (unsigned)y0 * (RES * FEAT);
            unsigned r1 = bpl + (unsigned)y1 * (RES * FEAT);
            unsigned cb = (unsigned)(s * 8);
            o00[pl] = r0 + (unsigned)x0 * FEAT + cb;
            o01[pl] = r0 + (unsigned)x1 * FEAT + cb;
            o10[pl] = r1 + (unsigned)x0 * FEAT + cb;
            o11[pl] = r1 + (unsigned)x1 * FEAT + cb;
        }

        uint2 r00[3], r01[3], r10[3], r11[3];
#pragma unroll
        for (int pl = 0; pl < 3; ++pl) {
            r00[pl] = *(const uint2*)(ws + o00[pl]);
            r01[pl] = *(const uint2*)(ws + o01[pl]);
            r10[pl] = *(const uint2*)(ws + o10[pl]);
            r11[pl] = *(const uint2*)(ws + o11[pl]);
        }

        const int trowBase = g * OUT_DIM;
#pragma unroll
        for (int pl = 0; pl < 3; ++pl) {
            float iwx = 1.0f - wxv[pl], iwy = 1.0f - wyv[pl];
            float w00 = iwx * iwy * FP8_INV_SCALE;
            float w01 = wxv[pl] * iwy * FP8_INV_SCALE;
            float w10 = iwx * wyv[pl] * FP8_INV_SCALE;
            float w11 = wxv[pl] * wyv[pl] * FP8_INV_SCALE;

            float a[8], b[8], c[8], d[8];
            floatx2 f;
            f = __builtin_amdgcn_cvt_pk_f32_fp8((int)r00[pl].x, false); a[0] = f.x; a[1] = f.y;
            f = __builtin_amdgcn_cvt_pk_f32_fp8((int)r00[pl].x, true);  a[2] = f.x; a[3] = f.y;
            f = __builtin_amdgcn_cvt_pk_f32_fp8((int)r00[pl].y, false); a[4] = f.x; a[5] = f.y;
            f = __builtin_amdgcn_cvt_pk_f32_fp8((int)r00[pl].y, true);  a[6] = f.x; a[7] = f.y;
            f = __builtin_amdgcn_cvt_pk_f32_fp8((int)r01[pl].x, false); b[0] = f.x; b[1] = f.y;
            f = __builtin_amdgcn_cvt_pk_f32_fp8((int)r01[pl].x, true);  b[2] = f.x; b[3] = f.y;
            f = __builtin_amdgcn_cvt_pk_f32_fp8((int)r01[pl].y, false); b[4] = f.x; b[5] = f.y;
            f = __builtin_amdgcn_cvt_pk_f32_fp8((int)r01[pl].y, true);  b[6] = f.x; b[7] = f.y;
            f = __builtin_amdgcn_cvt_pk_f32_fp8((int)r10[pl].x, false); c[0] = f.x; c[1] = f.y;
            f = __builtin_amdgcn_cvt_pk_f32_fp8((int)r10[pl].x, true);  c[2] = f.x; c[3] = f.y;
            f = __builtin_amdgcn_cvt_pk_f32_fp8((int)r10[pl].y, false); c[4] = f.x; c[5] = f.y;
            f = __builtin_amdgcn_cvt_pk_f32_fp8((int)r10[pl].y, true);  c[6] = f.x; c[7] = f.y;
            f = __builtin_amdgcn_cvt_pk_f32_fp8((int)r11[pl].x, false); d[0] = f.x; d[1] = f.y;
            f = __builtin_amdgcn_cvt_pk_f32_fp8((int)r11[pl].x, true);  d[2] = f.x; d[3] = f.y;
            f = __builtin_amdgcn_cvt_pk_f32_fp8((int)r11[pl].y, false); d[4] = f.x; d[5] = f.y;
            f = __builtin_amdgcn_cvt_pk_f32_fp8((int)r11[pl].y, true);  d[6] = f.x; d[7] = f.y;

#pragma unroll
            for (int k = 0; k < 8; ++k) {
                float v = w00 * a[k] + w01 * b[k] + w10 * c[k] + w11 * d[k];
                tile[trowBase + pl * 32 + s * 8 + k] = __float2half(v);
            }
        }

        // posenc via double-angle recurrence
        const int peBase = trowBase + 96;
        if (s == 3) {
            tile[peBase + 0] = __float2half(X);
            tile[peBase + 1] = __float2half(Y);
            tile[peBase + 2] = __float2half(Z);
        } else {
            float ax = (s == 0) ? X : (s == 1) ? Y : Z;
            float sn, cs;
            __sincosf(ax, &sn, &cs);
#pragma unroll
            for (int k = 0; k < 6; ++k) {
                tile[peBase + 3 + k * 6 + s]     = __float2half(sn);
                tile[peBase + 3 + k * 6 + 3 + s] = __float2half(cs);
                float s2 = sn + sn;
                sn = s2 * cs;
                cs = __builtin_fmaf(-s2, (s2 * 0.5f), 1.0f);
            }
        }
    }
    __syncthreads();

    // scattered row writes: 16 lanes per row, 64-B contiguous segments
    const int lane = t & 15;
    for (int rr = t >> 4; rr < m; rr += 16) {
        float* dst = out + (size_t)sIdx[rr] * OUT_DIM;
        const __half* src = tile + rr * OUT_DIM;
        for (int k = lane; k < OUT_DIM; k += 16)
            __builtin_nontemporal_store(__half2float(src[k]), dst + k);
    }
}

extern "C" void kernel_launch(void* const* d_in, const int* in_sizes, int n_in,
                              void* d_out, int out_size, void* d_ws, size_t ws_size,
                              hipStream_t stream) {
    const float* p    = (const float*)d_in[0];
    const float* tri  = (const float*)d_in[1];
    const float* aabb = (const float*)d_in[2];
    float* out = (float*)d_out;
    unsigned char* ws = (unsigned char*)d_ws;

    int npts = in_sizes[0] / 3;

    unsigned* cnt    = (unsigned*)(ws + WS_CNT);
    unsigned* cursor = (unsigned*)(ws + WS_CURSOR);
    uint4*    sbuck  = (uint4*)(ws + WS_SBUCK);

    hipMemsetAsync(cnt, 0, NCELLS * sizeof(unsigned), stream);

    int npos = 3 * RES * RES;
    transpose_to_chlast_fp8<<<npos / 256, 256, 0, stream>>>(tri, ws);

    hist_kernel<<<HIST_BLOCKS, 256, 0, stream>>>(p, aabb, cnt, npts);
    scan_kernel<<<1, 256, 0, stream>>>(cnt, cursor);
    scatter_kernel<<<HIST_BLOCKS, 256, 0, stream>>>(p, aabb, cursor, sbuck, npts);

    int nb = (npts + PTS_PER_BLOCK - 1) / PTS_PER_BLOCK;
    triplane_sample_sorted<<<nb, 256, 0, stream>>>(ws, sbuck, out, npts, nb);
}

// Round 6
// 301.592 us; speedup vs baseline: 1.8195x; 1.8195x over previous
//
#include <hip/hip_runtime.h>
#include <hip/hip_fp16.h>

#define RES 512
#define FEAT 32
#define PLANE_ELEMS (RES * RES)                 // 262144
#define PLANE_CH_ELEMS (FEAT * PLANE_ELEMS)     // per plane (ch-first fp32)
#define PTS_PER_BLOCK 64
#define OUT_DIM 135
#define TILE_HALVES (PTS_PER_BLOCK * OUT_DIM)   // 8640 halves = 17280 B

#define FP8_SCALE 1024.0f
#define FP8_INV_SCALE (1.0f / 1024.0f)

#define NCELLS 4096                              // 16^3 Morton cells
#define HIST_BLOCKS 512

// ws layout (ws is ~2.1 GB; we use < 42 MB)
#define WS_PLANES 0u
#define WS_CNT    (24u << 20)                    // 4096 u32
#define WS_CURSOR ((24u << 20) + 16384u)         // 4096 u32
#define WS_SBUCK  (25u << 20)                    // npts x uint4 (16 MB)

typedef float floatx2 __attribute__((ext_vector_type(2)));
typedef float floatx4 __attribute__((ext_vector_type(4)));

// ---------------------------------------------------------------------------
// helpers
// ---------------------------------------------------------------------------
__device__ __forceinline__ unsigned spread4(unsigned v) {
    return (v & 1u) | ((v & 2u) << 2) | ((v & 4u) << 4) | ((v & 8u) << 6);
}

__device__ __forceinline__ void point_transform(
        const float* __restrict__ p, const float* __restrict__ aabb, int i,
        float& tx, float& ty, float& tz) {
    float a0x = aabb[0], a0y = aabb[1], a0z = aabb[2];
    float a1x = aabb[3], a1y = aabb[4], a1z = aabb[5];
    tx = fminf(fmaxf((p[3 * (size_t)i + 0] - a0x) / (a1x - a0x), 0.0f), 1.0f);
    ty = fminf(fmaxf((p[3 * (size_t)i + 1] - a0y) / (a1y - a0y), 0.0f), 1.0f);
    tz = fminf(fmaxf((p[3 * (size_t)i + 2] - a0z) / (a1z - a0z), 0.0f), 1.0f);
}

__device__ __forceinline__ unsigned cell_of(float tx, float ty, float tz) {
    unsigned cx = min(15u, (unsigned)(tx * 16.0f));
    unsigned cy = min(15u, (unsigned)(ty * 16.0f));
    unsigned cz = min(15u, (unsigned)(tz * 16.0f));
    return spread4(cx) | (spread4(cy) << 1) | (spread4(cz) << 2);
}

// ---------------------------------------------------------------------------
// Kernel 1: triplane [3][32][512][512] fp32 -> ws [3][512][512][32] fp8 e4m3
// ---------------------------------------------------------------------------
__global__ __launch_bounds__(256) void transpose_to_chlast_fp8(
        const float* __restrict__ tri, unsigned char* __restrict__ ws) {
    int idx = blockIdx.x * 256 + threadIdx.x;   // 0 .. 3*512*512-1
    int pl = idx >> 18;
    int rem = idx & (PLANE_ELEMS - 1);
    const float* src = tri + (size_t)pl * PLANE_CH_ELEMS + rem;

    float v[32];
#pragma unroll
    for (int c = 0; c < 32; ++c)
        v[c] = __builtin_nontemporal_load(src + (size_t)c * PLANE_ELEMS) * FP8_SCALE;

    union { unsigned int w[8]; uint4 u[2]; } buf;
#pragma unroll
    for (int d = 0; d < 8; ++d) {
        int w = 0;
        w = __builtin_amdgcn_cvt_pk_fp8_f32(v[4 * d + 0], v[4 * d + 1], w, false);
        w = __builtin_amdgcn_cvt_pk_fp8_f32(v[4 * d + 2], v[4 * d + 3], w, true);
        buf.w[d] = (unsigned int)w;
    }

    uint4* dst = (uint4*)(ws + (size_t)idx * FEAT);
    dst[0] = buf.u[0];
    dst[1] = buf.u[1];
}

// ---------------------------------------------------------------------------
// Kernel 2: histogram of points per Morton cell (LDS-aggregated).
// ---------------------------------------------------------------------------
__global__ __launch_bounds__(256) void hist_kernel(
        const float* __restrict__ p, const float* __restrict__ aabb,
        unsigned* __restrict__ cnt, int npts) {
    __shared__ unsigned h[NCELLS];
    for (int i = threadIdx.x; i < NCELLS; i += 256) h[i] = 0;
    __syncthreads();
    for (int i = blockIdx.x * 256 + threadIdx.x; i < npts; i += gridDim.x * 256) {
        float tx, ty, tz;
        point_transform(p, aabb, i, tx, ty, tz);
        atomicAdd(&h[cell_of(tx, ty, tz)], 1u);
    }
    __syncthreads();
    for (int i = threadIdx.x; i < NCELLS; i += 256) {
        unsigned v = h[i];
        if (v) atomicAdd(&cnt[i], v);
    }
}

// ---------------------------------------------------------------------------
// Kernel 3: exclusive scan of 4096 counters -> cursor (single block).
// ---------------------------------------------------------------------------
__global__ __launch_bounds__(256) void scan_kernel(
        const unsigned* __restrict__ cnt, unsigned* __restrict__ cursor) {
    __shared__ unsigned partial[256];
    int t = threadIdx.x;
    unsigned local[16];
    unsigned sum = 0;
#pragma unroll
    for (int k = 0; k < 16; ++k) { local[k] = sum; sum += cnt[t * 16 + k]; }
    partial[t] = sum;
    __syncthreads();
    for (int off = 1; off < 256; off <<= 1) {
        unsigned v = partial[t];
        if (t >= off) v += partial[t - off];
        __syncthreads();
        partial[t] = v;
        __syncthreads();
    }
    unsigned base = (t == 0) ? 0u : partial[t - 1];
#pragma unroll
    for (int k = 0; k < 16; ++k) cursor[t * 16 + k] = base + local[k];
}

// ---------------------------------------------------------------------------
// Kernel 4: scatter points into Morton-sorted compact array.
// ---------------------------------------------------------------------------
#define SCAT_KMAX 8
__global__ __launch_bounds__(256) void scatter_kernel(
        const float* __restrict__ p, const float* __restrict__ aabb,
        unsigned* __restrict__ cursor, uint4* __restrict__ sbuck, int npts) {
    __shared__ unsigned hcnt[NCELLS];
    __shared__ unsigned hbase[NCELLS];
    for (int i = threadIdx.x; i < NCELLS; i += 256) hcnt[i] = 0;
    __syncthreads();

    int chunk = (npts + gridDim.x - 1) / gridDim.x;
    int beg = blockIdx.x * chunk;
    int end = min(npts, beg + chunk);

    unsigned myCell[SCAT_KMAX], myRank[SCAT_KMAX];
    int myPt[SCAT_KMAX];
    int n = 0;
    for (int i = beg + threadIdx.x; i < end && n < SCAT_KMAX; i += 256) {
        float tx, ty, tz;
        point_transform(p, aabb, i, tx, ty, tz);
        unsigned c = cell_of(tx, ty, tz);
        myCell[n] = c;
        myRank[n] = atomicAdd(&hcnt[c], 1u);
        myPt[n] = i;
        ++n;
    }
    __syncthreads();
    for (int i = threadIdx.x; i < NCELLS; i += 256) {
        unsigned v = hcnt[i];
        hbase[i] = v ? atomicAdd(&cursor[i], v) : 0u;
    }
    __syncthreads();
    for (int k = 0; k < n; ++k) {
        int i = myPt[k];
        float tx, ty, tz;
        point_transform(p, aabb, i, tx, ty, tz);
        float X = 2.0f * tx - 1.0f, Y = 2.0f * ty - 1.0f, Z = 2.0f * tz - 1.0f;
        unsigned slot = hbase[myCell[k]] + myRank[k];
        uint4 v;
        v.x = __float_as_uint(X); v.y = __float_as_uint(Y);
        v.z = __float_as_uint(Z); v.w = (unsigned)i;
        sbuck[slot] = v;
    }
}

// ---------------------------------------------------------------------------
// Kernel 5: sample + posenc over Morton-sorted points.
// Scattered row writes now go wave-per-row, dword-coalesced, THROUGH L2
// (no NT) so write-combining assembles full lines.
// ---------------------------------------------------------------------------
__global__ __launch_bounds__(256, 6) void triplane_sample_sorted(
        const unsigned char* __restrict__ ws, const uint4* __restrict__ sbuck,
        float* __restrict__ out, int npts, int nb) {
    __shared__ __align__(16) __half tile[TILE_HALVES];   // 17280 B
    __shared__ int sIdx[PTS_PER_BLOCK];

    // bijective chunked XCD swizzle: each XCD gets a contiguous Morton range
    int orig = blockIdx.x;
    int xcd = orig & 7, j = orig >> 3;
    int q = nb >> 3, r = nb & 7;
    int wg = (xcd < r ? xcd * (q + 1) : r * (q + 1) + (xcd - r) * q) + j;

    int base = wg * PTS_PER_BLOCK;
    int m = min(PTS_PER_BLOCK, npts - base);
    if (m <= 0) return;

    const int t = threadIdx.x;
    const int g = t >> 2;         // point row within block
    const int s = t & 3;          // sub-thread (channel chunk)
    const bool act = g < m;

    float X = 0.f, Y = 0.f, Z = 0.f;
    if (act) {
        uint4 pt = sbuck[base + g];
        X = __uint_as_float(pt.x);
        Y = __uint_as_float(pt.y);
        Z = __uint_as_float(pt.z);
        if (s == 0) sIdx[g] = (int)pt.w;
    }

    if (act) {
        // plane 0: (gx=X, gy=Y); plane 1: (gx=Y, gy=Z); plane 2: (gx=X, gy=Z)
        float gxs[3] = {X, Y, X};
        float gys[3] = {Y, Z, Z};
        unsigned o00[3], o01[3], o10[3], o11[3];
        float wxv[3], wyv[3];
#pragma unroll
        for (int pl = 0; pl < 3; ++pl) {
            float fx = (gxs[pl] + 1.0f) * (0.5f * (RES - 1));
            float fy = (gys[pl] + 1.0f) * (0.5f * (RES - 1));
            float x0f = floorf(fx), y0f = floorf(fy);
            wxv[pl] = fx - x0f;
            wyv[pl] = fy - y0f;
            int x0 = min(max((int)x0f, 0), RES - 1);
            int x1 = min(x0 + 1, RES - 1);
            int y0 = min(max((int)y0f, 0), RES - 1);
            int y1 = min(y0 + 1, RES - 1);
            unsigned bpl = (unsigned)pl * (PLANE_ELEMS * FEAT);
            unsigned r0 = bpl + (unsigned)y0 * (RES * FEAT);
            unsigned r1 = bpl + (unsigned)y1 * (RES * FEAT);
            unsigned cb = (unsigned)(s * 8);
            o00[pl] = r0 + (unsigned)x0 * FEAT + cb;
            o01[pl] = r0 + (unsigned)x1 * FEAT + cb;
            o10[pl] = r1 + (unsigned)x0 * FEAT + cb;
            o11[pl] = r1 + (unsigned)x1 * FEAT + cb;
        }

        uint2 r00[3], r01[3], r10[3], r11[3];
#pragma unroll
        for (int pl = 0; pl < 3; ++pl) {
            r00[pl] = *(const uint2*)(ws + o00[pl]);
            r01[pl] = *(const uint2*)(ws + o01[pl]);
            r10[pl] = *(const uint2*)(ws + o10[pl]);
            r11[pl] = *(const uint2*)(ws + o11[pl]);
        }

        const int trowBase = g * OUT_DIM;
#pragma unroll
        for (int pl = 0; pl < 3; ++pl) {
            float iwx = 1.0f - wxv[pl], iwy = 1.0f - wyv[pl];
            float w00 = iwx * iwy * FP8_INV_SCALE;
            float w01 = wxv[pl] * iwy * FP8_INV_SCALE;
            float w10 = iwx * wyv[pl] * FP8_INV_SCALE;
            float w11 = wxv[pl] * wyv[pl] * FP8_INV_SCALE;

            float a[8], b[8], c[8], d[8];
            floatx2 f;
            f = __builtin_amdgcn_cvt_pk_f32_fp8((int)r00[pl].x, false); a[0] = f.x; a[1] = f.y;
            f = __builtin_amdgcn_cvt_pk_f32_fp8((int)r00[pl].x, true);  a[2] = f.x; a[3] = f.y;
            f = __builtin_amdgcn_cvt_pk_f32_fp8((int)r00[pl].y, false); a[4] = f.x; a[5] = f.y;
            f = __builtin_amdgcn_cvt_pk_f32_fp8((int)r00[pl].y, true);  a[6] = f.x; a[7] = f.y;
            f = __builtin_amdgcn_cvt_pk_f32_fp8((int)r01[pl].x, false); b[0] = f.x; b[1] = f.y;
            f = __builtin_amdgcn_cvt_pk_f32_fp8((int)r01[pl].x, true);  b[2] = f.x; b[3] = f.y;
            f = __builtin_amdgcn_cvt_pk_f32_fp8((int)r01[pl].y, false); b[4] = f.x; b[5] = f.y;
            f = __builtin_amdgcn_cvt_pk_f32_fp8((int)r01[pl].y, true);  b[6] = f.x; b[7] = f.y;
            f = __builtin_amdgcn_cvt_pk_f32_fp8((int)r10[pl].x, false); c[0] = f.x; c[1] = f.y;
            f = __builtin_amdgcn_cvt_pk_f32_fp8((int)r10[pl].x, true);  c[2] = f.x; c[3] = f.y;
            f = __builtin_amdgcn_cvt_pk_f32_fp8((int)r10[pl].y, false); c[4] = f.x; c[5] = f.y;
            f = __builtin_amdgcn_cvt_pk_f32_fp8((int)r10[pl].y, true);  c[6] = f.x; c[7] = f.y;
            f = __builtin_amdgcn_cvt_pk_f32_fp8((int)r11[pl].x, false); d[0] = f.x; d[1] = f.y;
            f = __builtin_amdgcn_cvt_pk_f32_fp8((int)r11[pl].x, true);  d[2] = f.x; d[3] = f.y;
            f = __builtin_amdgcn_cvt_pk_f32_fp8((int)r11[pl].y, false); d[4] = f.x; d[5] = f.y;
            f = __builtin_amdgcn_cvt_pk_f32_fp8((int)r11[pl].y, true);  d[6] = f.x; d[7] = f.y;

#pragma unroll
            for (int k = 0; k < 8; ++k) {
                float v = w00 * a[k] + w01 * b[k] + w10 * c[k] + w11 * d[k];
                tile[trowBase + pl * 32 + s * 8 + k] = __float2half(v);
            }
        }

        // posenc via double-angle recurrence
        const int peBase = trowBase + 96;
        if (s == 3) {
            tile[peBase + 0] = __float2half(X);
            tile[peBase + 1] = __float2half(Y);
            tile[peBase + 2] = __float2half(Z);
        } else {
            float ax = (s == 0) ? X : (s == 1) ? Y : Z;
            float sn, cs;
            __sincosf(ax, &sn, &cs);
#pragma unroll
            for (int k = 0; k < 6; ++k) {
                tile[peBase + 3 + k * 6 + s]     = __float2half(sn);
                tile[peBase + 3 + k * 6 + 3 + s] = __float2half(cs);
                float s2 = sn + sn;
                sn = s2 * cs;
                cs = __builtin_fmaf(-s2, (s2 * 0.5f), 1.0f);
            }
        }
    }
    __syncthreads();

    // ---- wave-per-row, dword-coalesced scattered writes (through L2) ----
    const int wave = t >> 6;      // 0..3
    const int lane = t & 63;
    for (int rr = wave; rr < m; rr += 4) {
        float* dst = out + (size_t)sIdx[rr] * OUT_DIM;
        const __half* src = tile + rr * OUT_DIM;
        dst[lane]      = __half2float(src[lane]);
        dst[64 + lane] = __half2float(src[64 + lane]);
        if (lane < OUT_DIM - 128)
            dst[128 + lane] = __half2float(src[128 + lane]);
    }
}

extern "C" void kernel_launch(void* const* d_in, const int* in_sizes, int n_in,
                              void* d_out, int out_size, void* d_ws, size_t ws_size,
                              hipStream_t stream) {
    const float* p    = (const float*)d_in[0];
    const float* tri  = (const float*)d_in[1];
    const float* aabb = (const float*)d_in[2];
    float* out = (float*)d_out;
    unsigned char* ws = (unsigned char*)d_ws;

    int npts = in_sizes[0] / 3;

    unsigned* cnt    = (unsigned*)(ws + WS_CNT);
    unsigned* cursor = (unsigned*)(ws + WS_CURSOR);
    uint4*    sbuck  = (uint4*)(ws + WS_SBUCK);

    hipMemsetAsync(cnt, 0, NCELLS * sizeof(unsigned), stream);

    int npos = 3 * RES * RES;
    transpose_to_chlast_fp8<<<npos / 256, 256, 0, stream>>>(tri, ws);

    hist_kernel<<<HIST_BLOCKS, 256, 0, stream>>>(p, aabb, cnt, npts);
    scan_kernel<<<1, 256, 0, stream>>>(cnt, cursor);
    scatter_kernel<<<HIST_BLOCKS, 256, 0, stream>>>(p, aabb, cursor, sbuck, npts);

    int nb = (npts + PTS_PER_BLOCK - 1) / PTS_PER_BLOCK;
    triplane_sample_sorted<<<nb, 256, 0, stream>>>(ws, sbuck, out, npts, nb);
}

// Round 7
// 177.863 us; speedup vs baseline: 3.0853x; 1.6956x over previous
//
#include <hip/hip_runtime.h>
#include <hip/hip_fp16.h>

#define RES 512
#define FEAT 32
#define PLANE_ELEMS (RES * RES)                 // 262144
#define PLANE_CH_ELEMS (FEAT * PLANE_ELEMS)     // per plane (ch-first fp32)
#define PTS_PER_BLOCK 64
#define OUT_DIM 135
#define TILE_HALVES (PTS_PER_BLOCK * OUT_DIM)   // 8640 halves = 17280 B
#define REC_BYTES 64                             // one (x,y) record: 32ch x (y,y+1) fp8

#define FP8_SCALE 1024.0f
#define FP8_INV_SCALE (1.0f / 1024.0f)

typedef float floatx2 __attribute__((ext_vector_type(2)));
typedef float floatx4 __attribute__((ext_vector_type(4)));

// ---------------------------------------------------------------------------
// Kernel 1: triplane [3][32][512][512] fp32 -> ws records.
// Record r = (pl, y, x): 64 B = 32 channel-pairs (fp8(v[y][c]), fp8(v[y+1][c]))
// with y+1 clamped to 511. A bilinear sample then needs only records
// (x0,y0) and (x1,y0): each holds BOTH y-rows for its column.
// ---------------------------------------------------------------------------
__global__ __launch_bounds__(256) void build_records_fp8(
        const float* __restrict__ tri, unsigned char* __restrict__ ws) {
    int idx = blockIdx.x * 256 + threadIdx.x;   // 0 .. 3*512*512-1
    int pl = idx >> 18;
    int rem = idx & (PLANE_ELEMS - 1);
    int y = rem >> 9;
    int y1 = min(y + 1, RES - 1);
    int x = rem & (RES - 1);

    const float* s0 = tri + (size_t)pl * PLANE_CH_ELEMS + y  * RES + x;
    const float* s1 = tri + (size_t)pl * PLANE_CH_ELEMS + y1 * RES + x;

    union { unsigned int w[16]; uint4 u[4]; } buf;
#pragma unroll
    for (int d = 0; d < 16; ++d) {
        int c0 = 2 * d, c1 = 2 * d + 1;
        float vy0 = s0[(size_t)c0 * PLANE_ELEMS] * FP8_SCALE;
        float vn0 = s1[(size_t)c0 * PLANE_ELEMS] * FP8_SCALE;
        float vy1 = s0[(size_t)c1 * PLANE_ELEMS] * FP8_SCALE;
        float vn1 = s1[(size_t)c1 * PLANE_ELEMS] * FP8_SCALE;
        int w = 0;
        w = __builtin_amdgcn_cvt_pk_fp8_f32(vy0, vn0, w, false);  // bytes 0,1
        w = __builtin_amdgcn_cvt_pk_fp8_f32(vy1, vn1, w, true);   // bytes 2,3
        buf.w[d] = (unsigned int)w;
    }

    uint4* dst = (uint4*)(ws + (size_t)idx * REC_BYTES);
#pragma unroll
    for (int j = 0; j < 4; ++j) dst[j] = buf.u[j];
}

// ---------------------------------------------------------------------------
// Kernel 2: sample + posenc. 256 threads / 64 points (4 threads per point).
// Per point: 6 record fetches (2 x-corners x 3 planes), each a fully-used
// aligned 64-B line (4-lane uint4 groups). fp16 LDS staging, coalesced NT
// float4 output writes.
// ---------------------------------------------------------------------------
__global__ __launch_bounds__(256, 6) void triplane_sample(
        const float* __restrict__ p, const unsigned char* __restrict__ ws,
        const float* __restrict__ aabb, float* __restrict__ out, int npts) {
    __shared__ __align__(16) __half tile[TILE_HALVES];   // 17280 B

    const int t = threadIdx.x;
    const int q = t >> 2;         // point within block
    const int s = t & 3;          // sub-thread: channels 8s..8s+7
    const int blockBase = blockIdx.x * PTS_PER_BLOCK;

    // ---- point params (redundant x4 per point) ----
    int i = blockBase + q;
    int ii = (i < npts) ? i : (npts - 1);
    float px = p[(size_t)ii * 3 + 0];
    float py = p[(size_t)ii * 3 + 1];
    float pz = p[(size_t)ii * 3 + 2];
    float a0x = aabb[0], a0y = aabb[1], a0z = aabb[2];
    float a1x = aabb[3], a1y = aabb[4], a1z = aabb[5];

    float tx = fminf(fmaxf((px - a0x) / (a1x - a0x), 0.0f), 1.0f);
    float ty = fminf(fmaxf((py - a0y) / (a1y - a0y), 0.0f), 1.0f);
    float tz = fminf(fmaxf((pz - a0z) / (a1z - a0z), 0.0f), 1.0f);
    float X = 2.0f * tx - 1.0f;
    float Y = 2.0f * ty - 1.0f;
    float Z = 2.0f * tz - 1.0f;

    // plane 0: (gx=X, gy=Y); plane 1: (gx=Y, gy=Z); plane 2: (gx=X, gy=Z)
    float gxs[3] = {X, Y, X};
    float gys[3] = {Y, Z, Z};
    unsigned oA[3], oB[3];
    float wxv[3], wyv[3];
#pragma unroll
    for (int pl = 0; pl < 3; ++pl) {
        float fx = (gxs[pl] + 1.0f) * (0.5f * (RES - 1));
        float fy = (gys[pl] + 1.0f) * (0.5f * (RES - 1));
        float x0f = floorf(fx), y0f = floorf(fy);
        wxv[pl] = fx - x0f;
        wyv[pl] = fy - y0f;
        int x0 = min(max((int)x0f, 0), RES - 1);
        int x1 = min(x0 + 1, RES - 1);
        int y0 = min(max((int)y0f, 0), RES - 1);
        unsigned rbase = ((unsigned)pl * PLANE_ELEMS + (unsigned)y0 * RES) * REC_BYTES
                       + (unsigned)(s * 16);
        oA[pl] = rbase + (unsigned)x0 * REC_BYTES;
        oB[pl] = rbase + (unsigned)x1 * REC_BYTES;
    }

    // ---- issue all 6 record loads ----
    uint4 rA[3], rB[3];
#pragma unroll
    for (int pl = 0; pl < 3; ++pl) {
        rA[pl] = *(const uint4*)(ws + oA[pl]);
        rB[pl] = *(const uint4*)(ws + oB[pl]);
    }

    // ---- decode + bilinear, stage fp16 ----
    const int trowBase = q * OUT_DIM;
#pragma unroll
    for (int pl = 0; pl < 3; ++pl) {
        float iwx = 1.0f - wxv[pl], iwy = 1.0f - wyv[pl];
        float w00 = iwx * iwy * FP8_INV_SCALE;      // (x0, y0)
        float w01 = wxv[pl] * iwy * FP8_INV_SCALE;  // (x1, y0)
        float w10 = iwx * wyv[pl] * FP8_INV_SCALE;  // (x0, y1)
        float w11 = wxv[pl] * wyv[pl] * FP8_INV_SCALE;

        const unsigned int* wa = (const unsigned int*)&rA[pl];
        const unsigned int* wb = (const unsigned int*)&rB[pl];
#pragma unroll
        for (int j = 0; j < 4; ++j) {
            // dword j covers channels c=8s+2j, 8s+2j+1 as pairs (v[y0], v[y1])
            floatx2 f0 = __builtin_amdgcn_cvt_pk_f32_fp8((int)wa[j], false); // c, x0: (v00, v10)
            floatx2 f1 = __builtin_amdgcn_cvt_pk_f32_fp8((int)wa[j], true);  // c+1
            floatx2 g0 = __builtin_amdgcn_cvt_pk_f32_fp8((int)wb[j], false); // c, x1: (v01, v11)
            floatx2 g1 = __builtin_amdgcn_cvt_pk_f32_fp8((int)wb[j], true);

            float vA = w00 * f0.x + w10 * f0.y + w01 * g0.x + w11 * g0.y;
            float vB = w00 * f1.x + w10 * f1.y + w01 * g1.x + w11 * g1.y;
            int c = s * 8 + 2 * j;
            tile[trowBase + pl * 32 + c]     = __float2half(vA);
            tile[trowBase + pl * 32 + c + 1] = __float2half(vB);
        }
    }

    // ---- posenc via double-angle recurrence ----
    {
        const int peBase = trowBase + 96;
        if (s == 3) {
            tile[peBase + 0] = __float2half(X);
            tile[peBase + 1] = __float2half(Y);
            tile[peBase + 2] = __float2half(Z);
        } else {
            float ax = (s == 0) ? X : (s == 1) ? Y : Z;
            float sn, cs;
            __sincosf(ax, &sn, &cs);
#pragma unroll
            for (int k = 0; k < 6; ++k) {
                tile[peBase + 3 + k * 6 + s]     = __float2half(sn);
                tile[peBase + 3 + k * 6 + 3 + s] = __float2half(cs);
                float s2 = sn + sn;
                sn = s2 * cs;                                   // sin(2a)
                cs = __builtin_fmaf(-s2, (s2 * 0.5f), 1.0f);    // cos(2a)
            }
        }
    }
    __syncthreads();

    // ---- coalesced NT float4 output writes ----
    if (blockBase + PTS_PER_BLOCK <= npts) {
        const uint2* tp = (const uint2*)tile;
        floatx4* ov = (floatx4*)(out + (size_t)blockBase * OUT_DIM);
#pragma unroll 1
        for (int v = t; v < TILE_HALVES / 4; v += 256) {
            union { uint2 u; __half2 h2[2]; } x;
            x.u = tp[v];
            float2 f0 = __half22float2(x.h2[0]);
            float2 f1 = __half22float2(x.h2[1]);
            floatx4 val = {f0.x, f0.y, f1.x, f1.y};
            __builtin_nontemporal_store(val, ov + v);
        }
    } else {
        int valid = (npts - blockBase) * OUT_DIM;
        float* ob = out + (size_t)blockBase * OUT_DIM;
        for (int v = t; v < valid; v += 256)
            __builtin_nontemporal_store(__half2float(tile[v]), ob + v);
    }
}

extern "C" void kernel_launch(void* const* d_in, const int* in_sizes, int n_in,
                              void* d_out, int out_size, void* d_ws, size_t ws_size,
                              hipStream_t stream) {
    const float* p    = (const float*)d_in[0];
    const float* tri  = (const float*)d_in[1];
    const float* aabb = (const float*)d_in[2];
    float* out = (float*)d_out;
    unsigned char* ws = (unsigned char*)d_ws;

    int npts = in_sizes[0] / 3;

    int nrec = 3 * RES * RES;                   // 786432 records, 48 MB
    build_records_fp8<<<nrec / 256, 256, 0, stream>>>(tri, ws);

    int nblocks = (npts + PTS_PER_BLOCK - 1) / PTS_PER_BLOCK;
    triplane_sample<<<nblocks, 256, 0, stream>>>(p, ws, aabb, out, npts);
}